// Round 6
// baseline (646.081 us; speedup 1.0000x reference)
//
#include <hip/hip_runtime.h>

// ---------------------------------------------------------------------------
// GLMAttention: qkv proj (+RoPE) -> fused flash attn (scores out + softmax+PV)
// -> output proj.  All matmuls fp16 MFMA (16x16x32), f32 accumulate.
// B=4 S=1024 HID=2048 H=16 D=128.
// Round 6: flash = BARRIER-FREE. K/V MFMA fragments read directly from
// global (L1/L2-resident planes; all 4 waves read identical addrs -> L1
// broadcast). No __syncthreads, no vmcnt(0) drain in the loop; LDS = per-wave
// P buffer only (8 KB). Latency hidden by free-running TLP.
// ---------------------------------------------------------------------------

#define B_  4
#define S_  1024
#define HID_ 2048
#define H_  16
#define D_  128
#define RSQRT_D 0.08838834764831845f

typedef _Float16 f16x8 __attribute__((ext_vector_type(8)));
typedef _Float16 f16x4 __attribute__((ext_vector_type(4)));
typedef float f32x4 __attribute__((ext_vector_type(4)));

#define MFMA16(a, b, c) __builtin_amdgcn_mfma_f32_16x16x32_f16(a, b, c, 0, 0, 0)

__device__ __forceinline__ void gll16(const void* g, void* l) {
  __builtin_amdgcn_global_load_lds(
      (const __attribute__((address_space(1))) void*)g,
      (__attribute__((address_space(3))) void*)l, 16, 0, 0);
}

// ---------------------------------------------------------------------------
// RoPE tables: cos/sin[pos][j], j in [0,32), inv_freq = 10000^(-j/32)
// ---------------------------------------------------------------------------
__global__ void rope_table_kernel(float* __restrict__ tcos, float* __restrict__ tsin) {
  int i = blockIdx.x * blockDim.x + threadIdx.x;  // 32768 = 1024*32
  int pos = i >> 5, j = i & 31;
  float inv = expf(-(float)j * (9.210340371976184f / 32.0f));  // ln(10000)/32
  float ang = (float)pos * inv;
  tcos[i] = cosf(ang);
  tsin[i] = sinf(ang);
}

// ---------------------------------------------------------------------------
// f32 -> f16 convert, 8 elems/thread, vectorized
// ---------------------------------------------------------------------------
__global__ void cvt_kernel(const float* __restrict__ in, _Float16* __restrict__ out, int n8) {
  int i = blockIdx.x * blockDim.x + threadIdx.x;
  if (i >= n8) return;
  const f32x4* in4 = (const f32x4*)in;
  f32x4 a = in4[i * 2], b = in4[i * 2 + 1];
  f16x8 v;
  v[0] = (_Float16)a[0]; v[1] = (_Float16)a[1]; v[2] = (_Float16)a[2]; v[3] = (_Float16)a[3];
  v[4] = (_Float16)b[0]; v[5] = (_Float16)b[1]; v[6] = (_Float16)b[2]; v[7] = (_Float16)b[3];
  *(f16x8*)(out + (size_t)i * 8) = v;
}

// ---------------------------------------------------------------------------
// GEMM: C = A(MxK) @ W(NxK)^T + bias.  128x128 tile, BK=64, 4 waves, 4x4 frags.
// MODE 0: RoPE epilogue  -> f16 out (B,H,S,D)
// MODE 1: V head, transposed -> f16 out (B,H,D,S)
// MODE 2: f32 + bias     -> f32 out (M,N)  (final output)
// ---------------------------------------------------------------------------
template <int MODE>
__global__ __launch_bounds__(256) void proj_kernel(
    const _Float16* __restrict__ A, const _Float16* __restrict__ Bw,
    const float* __restrict__ bias, void* __restrict__ outp,
    const int* __restrict__ pids, const float* __restrict__ tcos,
    const float* __restrict__ tsin) {
  constexpr int N = HID_, K = HID_;
  constexpr int BK = 64;
  __shared__ _Float16 As[128 * BK];
  __shared__ _Float16 Bs[128 * BK];

  const int tid = threadIdx.x;
  // XCD-aware swizzle (512 blocks, 512%8==0 -> bijective)
  const int bid = (blockIdx.x & 7) * 64 + (blockIdx.x >> 3);
  const int tm = bid >> 4, tn = bid & 15;  // 32 x 16 tiles
  const int m0 = tm * 128, n0 = tn * 128;
  const int w = tid >> 6, l = tid & 63;
  const int mw = (w >> 1) * 64, nw = (w & 1) * 64;
  const int lr = l & 15, lh = l >> 4;

  f32x4 acc[4][4] = {};

  for (int kt = 0; kt < K / BK; ++kt) {
    const int k0 = kt * BK;
    __syncthreads();
#pragma unroll
    for (int i = 0; i < 4; ++i) {
      const int e = i * 2048 + tid * 8;
      gll16(A + (size_t)(m0 + (e >> 6)) * K + k0 + (e & 63), As + e);
      gll16(Bw + (size_t)(n0 + (e >> 6)) * K + k0 + (e & 63), Bs + e);
    }
    asm volatile("s_waitcnt vmcnt(0)" ::: "memory");
    __syncthreads();
#pragma unroll
    for (int kk = 0; kk < 2; ++kk) {
      f16x8 af[4], bf[4];
#pragma unroll
      for (int mi = 0; mi < 4; ++mi)
        af[mi] = *(const f16x8*)(As + (mw + mi * 16 + lr) * BK + kk * 32 + lh * 8);
#pragma unroll
      for (int ni = 0; ni < 4; ++ni)
        bf[ni] = *(const f16x8*)(Bs + (nw + ni * 16 + lr) * BK + kk * 32 + lh * 8);
#pragma unroll
      for (int mi = 0; mi < 4; ++mi)
#pragma unroll
        for (int ni = 0; ni < 4; ++ni)
          acc[mi][ni] = MFMA16(af[mi], bf[ni], acc[mi][ni]);
    }
  }

  if constexpr (MODE == 2) {
    float* out = (float*)outp;
#pragma unroll
    for (int mi = 0; mi < 4; ++mi)
#pragma unroll
      for (int ni = 0; ni < 4; ++ni) {
        const int col = n0 + nw + ni * 16 + lr;
        const float bb = bias[col];
#pragma unroll
        for (int r = 0; r < 4; ++r) {
          const int row = m0 + mw + mi * 16 + lh * 4 + r;
          out[(size_t)row * N + col] = acc[mi][ni][r] + bb;
        }
      }
  } else if constexpr (MODE == 1) {  // V: write (B,H,D,S) directly
    _Float16* out = (_Float16*)outp;
#pragma unroll
    for (int mi = 0; mi < 4; ++mi)
#pragma unroll
      for (int ni = 0; ni < 4; ++ni) {
        const int col = n0 + nw + ni * 16 + lr;
        const float bb = bias[col];
        const int h = col >> 7, hd = col & 127;
#pragma unroll
        for (int r = 0; r < 4; ++r) {
          const int row = m0 + mw + mi * 16 + lh * 4 + r;
          const int b = row >> 10, s = row & 1023;
          out[(((size_t)(b * H_ + h)) * D_ + hd) * S_ + s] = (_Float16)(acc[mi][ni][r] + bb);
        }
      }
  } else {  // MODE 0: RoPE. wave covers cols [c0,c0+64) = head dims [0,64) or [64,128)
    _Float16* out = (_Float16*)outp;
    const int sel = (nw >> 6) & 1;  // 0 -> pid row, 1 -> bid row of position_ids
#pragma unroll
    for (int mi = 0; mi < 4; ++mi) {
#pragma unroll
      for (int r = 0; r < 4; ++r) {
        const int row = m0 + mw + mi * 16 + lh * 4 + r;
        const int b = row >> 10, s = row & 1023;
        const int pos = pids[b * 2 * S_ + sel * S_ + s];
#pragma unroll
        for (int ni = 0; ni < 2; ++ni) {
          const int col = n0 + nw + ni * 16 + lr;  // first of (d, d+32) pair
          const int j = ni * 16 + lr;              // 0..31 freq index
          const float c = tcos[pos * 32 + j];
          const float sn = tsin[pos * 32 + j];
          const float x1 = acc[mi][ni][r] + bias[col];
          const float x2 = acc[mi][ni + 2][r] + bias[col + 32];
          const int h = col >> 7, hd = col & 127;
          const size_t base = (((size_t)(b * H_ + h)) * S_ + s) * D_;
          out[base + hd] = (_Float16)(x1 * c - x2 * sn);
          out[base + hd + 32] = (_Float16)(x2 * c + x1 * sn);
        }
      }
    }
  }
}

// ---------------------------------------------------------------------------
// Fused flash attention, barrier-free.
// Block = (b,h, 64 q-rows); 4 waves x 16 rows, fully independent (no
// __syncthreads anywhere). K/V fragments read directly from global: K/V tile
// working set is 32KB (L1-sized) and all 4 waves read IDENTICAL fragment
// addresses -> L1 broadcast; planes are L2-resident (XCD swizzle keeps the
// 8 planes/XCD inside one 4MB L2). Swapped MFMA operands as round 4.
// LDS = per-wave P buffer only (8 KB/block).
// ---------------------------------------------------------------------------
__global__ __launch_bounds__(256) void flash_kernel(
    const _Float16* __restrict__ q, const _Float16* __restrict__ k,
    const _Float16* __restrict__ vt, const float* __restrict__ pbias,
    const float* __restrict__ maskp, const float* __restrict__ prev,
    float* __restrict__ scores, _Float16* __restrict__ ctx) {
  constexpr int BT = 64;
  __shared__ _Float16 Ps[4][16 * BT]; // per-wave [q][t] swizzled, 8 KB

  const int tid = threadIdx.x, w = tid >> 6, l = tid & 63;
  const int lr = l & 15, lh = l >> 4;
  // XCD swizzle: 1024 blocks -> 128 consecutive per XCD (8 planes/XCD)
  const int sid = (blockIdx.x & 7) * 128 + (blockIdx.x >> 3);
  const int qt = sid & 15, byh = sid >> 4;
  const int b = byh >> 4, h = byh & 15;
  const size_t plane = (size_t)byh;
  const int q0 = qt * 64 + w * 16;
  const int qrow = q0 + lr;           // this lane's q-row
  const int swz = (lr & 7) << 3;      // element-index XOR for P-buffer

  const float* prow  = prev  + (plane * S_ + qrow) * S_;
  const float* pbrow = pbias + ((size_t)h * S_ + qrow) * S_;
  const float* mrow  = maskp + ((size_t)b * S_ + qrow) * S_;
  float*       srow  = scores + (plane * S_ + qrow) * S_;
  const _Float16* kpl = k  + plane * S_ * D_;
  const _Float16* vpl = vt + plane * D_ * S_;

  // Q B-fragments: lane provides Q[row=lr][k]
  f16x8 qa[4];
#pragma unroll
  for (int kk = 0; kk < 4; ++kk)
    qa[kk] = *(const f16x8*)(q + (plane * S_ + qrow) * D_ + kk * 32 + lh * 8);

  f32x4 o[8] = {};
  float m_r = -1e30f, l_r = 0.0f;

  for (int tt = 0; tt < S_ / BT; ++tt) {
    const int t0 = tt * BT;

    // issue HBM streams first (deepest latency); consumed after QK^T
    f32x4 pv4[4], pb4[4], mk4[4];
#pragma unroll
    for (int nt = 0; nt < 4; ++nt) {
      const int toff = t0 + nt * 16 + lh * 4;
      pv4[nt] = __builtin_nontemporal_load((const f32x4*)(prow + toff));
      pb4[nt] = *(const f32x4*)(pbrow + toff);
      mk4[nt] = *(const f32x4*)(mrow + toff);
    }

    // QK^T swapped, K fragments straight from global (L1-broadcast):
    // sa[nt][r] = S[t = t0+nt*16+lh*4+r][q = qrow]
    f32x4 sa[4] = {};
#pragma unroll
    for (int nt = 0; nt < 4; ++nt) {
      const int trow = t0 + nt * 16 + lr;
      __builtin_amdgcn_s_setprio(1);
#pragma unroll
      for (int kk = 0; kk < 4; ++kk) {
        const f16x8 kb = *(const f16x8*)(kpl + (size_t)trow * D_ + kk * 32 + lh * 8);
        sa[nt] = MFMA16(kb, qa[kk], sa[nt]);
      }
      __builtin_amdgcn_s_setprio(0);
    }

    // epilogue: score = (qk+pb)/sqrtD + mask + prev ; pure VALU + store
#pragma unroll
    for (int nt = 0; nt < 4; ++nt) {
      const int toff = t0 + nt * 16 + lh * 4;
      f32x4 sc4 = (sa[nt] + pb4[nt]) * RSQRT_D + mk4[nt] + pv4[nt];
      __builtin_nontemporal_store(sc4, (f32x4*)(srow + toff));
      sa[nt] = sc4;
    }

    // online softmax, one q-row per lane; row group = lanes {l, l^16, l^32, l^48}
    float tmx = -1e30f;
#pragma unroll
    for (int nt = 0; nt < 4; ++nt)
#pragma unroll
      for (int r = 0; r < 4; ++r) tmx = fmaxf(tmx, sa[nt][r]);
    tmx = fmaxf(tmx, __shfl_xor(tmx, 16));
    tmx = fmaxf(tmx, __shfl_xor(tmx, 32));
    if (!__all(tmx <= m_r + 8.0f)) {   // T13 defer-max
      const float newm = fmaxf(m_r, tmx);
      const float al = __expf(m_r - newm);
      m_r = newm;
      l_r *= al;
#pragma unroll
      for (int nd = 0; nd < 8; ++nd) o[nd] *= al;
    }
    float ts = 0.0f;
#pragma unroll
    for (int nt = 0; nt < 4; ++nt)
#pragma unroll
      for (int r = 0; r < 4; ++r) {
        const float pe = __expf(sa[nt][r] - m_r);
        sa[nt][r] = pe;
        ts += pe;
      }
    ts += __shfl_xor(ts, 16);
    ts += __shfl_xor(ts, 32);
    l_r += ts;

    // P -> per-wave LDS [q=lr][t], swizzled, f16x4 stores (wave-local, no barrier)
    _Float16* pw = &Ps[w][0];
#pragma unroll
    for (int nt = 0; nt < 4; ++nt) {
      f16x4 pk;
      pk[0] = (_Float16)sa[nt][0]; pk[1] = (_Float16)sa[nt][1];
      pk[2] = (_Float16)sa[nt][2]; pk[3] = (_Float16)sa[nt][3];
      *(f16x4*)(pw + lr * BT + ((nt * 16 + lh * 4) ^ swz)) = pk;
    }

    // PV swapped, V fragments straight from global: o[nd][r] = ctx[d][q]
#pragma unroll
    for (int kk2 = 0; kk2 < 2; ++kk2) {
      const f16x8 pa = *(const f16x8*)(pw + lr * BT + ((kk2 * 32 + lh * 8) ^ swz));
      __builtin_amdgcn_s_setprio(1);
#pragma unroll
      for (int nd = 0; nd < 8; ++nd) {
        const int vr = nd * 16 + lr;
        const f16x8 vb = *(const f16x8*)(vpl + (size_t)vr * S_ + t0 + kk2 * 32 + lh * 8);
        o[nd] = MFMA16(vb, pa, o[nd]);
      }
      __builtin_amdgcn_s_setprio(0);
    }
  }

  // ctx write: lane owns q-row qrow, d = nd*16 + lh*4 + r -> f16x4 stores
  const float inv_l = 1.0f / l_r;
  _Float16* crow = ctx + ((size_t)(b * S_) + qrow) * HID_ + h * D_;
#pragma unroll
  for (int nd = 0; nd < 8; ++nd) {
    f16x4 cv;
#pragma unroll
    for (int r = 0; r < 4; ++r) cv[r] = (_Float16)(o[nd][r] * inv_l);
    *(f16x4*)(crow + nd * 16 + lh * 4) = cv;
  }
}

// ---------------------------------------------------------------------------
extern "C" void kernel_launch(void* const* d_in, const int* in_sizes, int n_in,
                              void* d_out, int out_size, void* d_ws, size_t ws_size,
                              hipStream_t stream) {
  const float* query = (const float*)d_in[0];
  const float* key_i = (const float*)d_in[1];
  const float* value = (const float*)d_in[2];
  const float* maskp = (const float*)d_in[3];
  const float* pbias = (const float*)d_in[4];
  const float* prev  = (const float*)d_in[5];
  const int*   pids  = (const int*)d_in[6];
  const float* Wq = (const float*)d_in[7];
  const float* bq = (const float*)d_in[8];
  const float* Wk = (const float*)d_in[9];
  const float* bk = (const float*)d_in[10];
  const float* Wv = (const float*)d_in[11];
  const float* bv = (const float*)d_in[12];
  const float* Wo = (const float*)d_in[13];
  const float* bo = (const float*)d_in[14];

  char* ws = (char*)d_ws;
  // workspace layout (bytes); total need = 134,479,872
  const size_t OFF_TCOS = 0;
  const size_t OFF_TSIN = 131072;
  const size_t OFF_W    = 262144;                      // 4 x 8 MB f16 weights
  const size_t OFF_X    = OFF_W + 4ull * 8388608;      // 3 x 16 MB f16 X
  const size_t OFF_Q    = OFF_X + 3ull * 16777216;
  const size_t OFF_K    = OFF_Q + 16777216;
  const size_t OFF_VT   = OFF_K + 16777216;            // V proj writes here (B,H,D,S)
  const size_t OFF_CTX  = OFF_X + 16777216;            // reuse Xk (consumed)

  float* tcos = (float*)(ws + OFF_TCOS);
  float* tsin = (float*)(ws + OFF_TSIN);
  _Float16* Wq16 = (_Float16*)(ws + OFF_W);
  _Float16* Wk16 = (_Float16*)(ws + OFF_W + 8388608);
  _Float16* Wv16 = (_Float16*)(ws + OFF_W + 2ull * 8388608);
  _Float16* Wo16 = (_Float16*)(ws + OFF_W + 3ull * 8388608);
  _Float16* Xq16 = (_Float16*)(ws + OFF_X);
  _Float16* Xk16 = (_Float16*)(ws + OFF_X + 16777216);
  _Float16* Xv16 = (_Float16*)(ws + OFF_X + 2ull * 16777216);
  _Float16* q16  = (_Float16*)(ws + OFF_Q);
  _Float16* k16  = (_Float16*)(ws + OFF_K);
  _Float16* vt16 = (_Float16*)(ws + OFF_VT);
  _Float16* ctx16 = (_Float16*)(ws + OFF_CTX);

  float* out_f32 = (float*)d_out;                 // (B,S,HID) = 8,388,608
  float* scores  = (float*)d_out + 8388608;       // (B,H,S,S) = 67,108,864

  rope_table_kernel<<<128, 256, 0, stream>>>(tcos, tsin);

  cvt_kernel<<<2048, 256, 0, stream>>>(Wq, Wq16, 524288);
  cvt_kernel<<<2048, 256, 0, stream>>>(Wk, Wk16, 524288);
  cvt_kernel<<<2048, 256, 0, stream>>>(Wv, Wv16, 524288);
  cvt_kernel<<<2048, 256, 0, stream>>>(Wo, Wo16, 524288);
  cvt_kernel<<<4096, 256, 0, stream>>>(query, Xq16, 1048576);
  cvt_kernel<<<4096, 256, 0, stream>>>(key_i, Xk16, 1048576);
  cvt_kernel<<<4096, 256, 0, stream>>>(value, Xv16, 1048576);

  proj_kernel<0><<<512, 256, 0, stream>>>(Xq16, Wq16, bq, (void*)q16, pids, tcos, tsin);
  proj_kernel<0><<<512, 256, 0, stream>>>(Xk16, Wk16, bk, (void*)k16, pids, tcos, tsin);
  proj_kernel<1><<<512, 256, 0, stream>>>(Xv16, Wv16, bv, (void*)vt16, nullptr, nullptr, nullptr);

  flash_kernel<<<1024, 256, 0, stream>>>(q16, k16, vt16, pbias, maskp, prev,
                                         scores, ctx16);

  proj_kernel<2><<<512, 256, 0, stream>>>(ctx16, Wo16, bo, (void*)out_f32,
                                          nullptr, nullptr, nullptr);
}

// Round 7
// 474.236 us; speedup vs baseline: 1.3624x; 1.3624x over previous
//
#include <hip/hip_runtime.h>

// ---------------------------------------------------------------------------
// GLMAttention: qkv proj (+RoPE) -> fused flash attn (scores out + softmax+PV)
// -> output proj.  All matmuls fp16 MFMA (16x16x32), f32 accumulate.
// B=4 S=1024 HID=2048 H=16 D=128.
// Round 7: flash = round-4 structure + T3-minimum 2-phase double-buffered
// global_load_lds: STAGE(t+1) issued BEFORE compute(t), drained only by the
// end-of-iteration __syncthreads. No mid-loop vmcnt(0). LDS 72KB (2 blk/CU).
// ---------------------------------------------------------------------------

#define B_  4
#define S_  1024
#define HID_ 2048
#define H_  16
#define D_  128
#define RSQRT_D 0.08838834764831845f

typedef _Float16 f16x8 __attribute__((ext_vector_type(8)));
typedef _Float16 f16x4 __attribute__((ext_vector_type(4)));
typedef float f32x4 __attribute__((ext_vector_type(4)));

#define MFMA16(a, b, c) __builtin_amdgcn_mfma_f32_16x16x32_f16(a, b, c, 0, 0, 0)

__device__ __forceinline__ void gll16(const void* g, void* l) {
  __builtin_amdgcn_global_load_lds(
      (const __attribute__((address_space(1))) void*)g,
      (__attribute__((address_space(3))) void*)l, 16, 0, 0);
}

// ---------------------------------------------------------------------------
// RoPE tables: cos/sin[pos][j], j in [0,32), inv_freq = 10000^(-j/32)
// ---------------------------------------------------------------------------
__global__ void rope_table_kernel(float* __restrict__ tcos, float* __restrict__ tsin) {
  int i = blockIdx.x * blockDim.x + threadIdx.x;  // 32768 = 1024*32
  int pos = i >> 5, j = i & 31;
  float inv = expf(-(float)j * (9.210340371976184f / 32.0f));  // ln(10000)/32
  float ang = (float)pos * inv;
  tcos[i] = cosf(ang);
  tsin[i] = sinf(ang);
}

// ---------------------------------------------------------------------------
// f32 -> f16 convert, 8 elems/thread, vectorized
// ---------------------------------------------------------------------------
__global__ void cvt_kernel(const float* __restrict__ in, _Float16* __restrict__ out, int n8) {
  int i = blockIdx.x * blockDim.x + threadIdx.x;
  if (i >= n8) return;
  const f32x4* in4 = (const f32x4*)in;
  f32x4 a = in4[i * 2], b = in4[i * 2 + 1];
  f16x8 v;
  v[0] = (_Float16)a[0]; v[1] = (_Float16)a[1]; v[2] = (_Float16)a[2]; v[3] = (_Float16)a[3];
  v[4] = (_Float16)b[0]; v[5] = (_Float16)b[1]; v[6] = (_Float16)b[2]; v[7] = (_Float16)b[3];
  *(f16x8*)(out + (size_t)i * 8) = v;
}

// ---------------------------------------------------------------------------
// GEMM: C = A(MxK) @ W(NxK)^T + bias.  128x128 tile, BK=64, 4 waves, 4x4 frags.
// MODE 0: RoPE epilogue  -> f16 out (B,H,S,D)
// MODE 1: V head, transposed -> f16 out (B,H,D,S)
// MODE 2: f32 + bias     -> f32 out (M,N)  (final output)
// ---------------------------------------------------------------------------
template <int MODE>
__global__ __launch_bounds__(256) void proj_kernel(
    const _Float16* __restrict__ A, const _Float16* __restrict__ Bw,
    const float* __restrict__ bias, void* __restrict__ outp,
    const int* __restrict__ pids, const float* __restrict__ tcos,
    const float* __restrict__ tsin) {
  constexpr int N = HID_, K = HID_;
  constexpr int BK = 64;
  __shared__ _Float16 As[128 * BK];
  __shared__ _Float16 Bs[128 * BK];

  const int tid = threadIdx.x;
  // XCD-aware swizzle (512 blocks, 512%8==0 -> bijective)
  const int bid = (blockIdx.x & 7) * 64 + (blockIdx.x >> 3);
  const int tm = bid >> 4, tn = bid & 15;  // 32 x 16 tiles
  const int m0 = tm * 128, n0 = tn * 128;
  const int w = tid >> 6, l = tid & 63;
  const int mw = (w >> 1) * 64, nw = (w & 1) * 64;
  const int lr = l & 15, lh = l >> 4;

  f32x4 acc[4][4] = {};

  for (int kt = 0; kt < K / BK; ++kt) {
    const int k0 = kt * BK;
    __syncthreads();
#pragma unroll
    for (int i = 0; i < 4; ++i) {
      const int e = i * 2048 + tid * 8;
      gll16(A + (size_t)(m0 + (e >> 6)) * K + k0 + (e & 63), As + e);
      gll16(Bw + (size_t)(n0 + (e >> 6)) * K + k0 + (e & 63), Bs + e);
    }
    asm volatile("s_waitcnt vmcnt(0)" ::: "memory");
    __syncthreads();
#pragma unroll
    for (int kk = 0; kk < 2; ++kk) {
      f16x8 af[4], bf[4];
#pragma unroll
      for (int mi = 0; mi < 4; ++mi)
        af[mi] = *(const f16x8*)(As + (mw + mi * 16 + lr) * BK + kk * 32 + lh * 8);
#pragma unroll
      for (int ni = 0; ni < 4; ++ni)
        bf[ni] = *(const f16x8*)(Bs + (nw + ni * 16 + lr) * BK + kk * 32 + lh * 8);
#pragma unroll
      for (int mi = 0; mi < 4; ++mi)
#pragma unroll
        for (int ni = 0; ni < 4; ++ni)
          acc[mi][ni] = MFMA16(af[mi], bf[ni], acc[mi][ni]);
    }
  }

  if constexpr (MODE == 2) {
    float* out = (float*)outp;
#pragma unroll
    for (int mi = 0; mi < 4; ++mi)
#pragma unroll
      for (int ni = 0; ni < 4; ++ni) {
        const int col = n0 + nw + ni * 16 + lr;
        const float bb = bias[col];
#pragma unroll
        for (int r = 0; r < 4; ++r) {
          const int row = m0 + mw + mi * 16 + lh * 4 + r;
          out[(size_t)row * N + col] = acc[mi][ni][r] + bb;
        }
      }
  } else if constexpr (MODE == 1) {  // V: write (B,H,D,S) directly
    _Float16* out = (_Float16*)outp;
#pragma unroll
    for (int mi = 0; mi < 4; ++mi)
#pragma unroll
      for (int ni = 0; ni < 4; ++ni) {
        const int col = n0 + nw + ni * 16 + lr;
        const float bb = bias[col];
        const int h = col >> 7, hd = col & 127;
#pragma unroll
        for (int r = 0; r < 4; ++r) {
          const int row = m0 + mw + mi * 16 + lh * 4 + r;
          const int b = row >> 10, s = row & 1023;
          out[(((size_t)(b * H_ + h)) * D_ + hd) * S_ + s] = (_Float16)(acc[mi][ni][r] + bb);
        }
      }
  } else {  // MODE 0: RoPE. wave covers cols [c0,c0+64) = head dims [0,64) or [64,128)
    _Float16* out = (_Float16*)outp;
    const int sel = (nw >> 6) & 1;  // 0 -> pid row, 1 -> bid row of position_ids
#pragma unroll
    for (int mi = 0; mi < 4; ++mi) {
#pragma unroll
      for (int r = 0; r < 4; ++r) {
        const int row = m0 + mw + mi * 16 + lh * 4 + r;
        const int b = row >> 10, s = row & 1023;
        const int pos = pids[b * 2 * S_ + sel * S_ + s];
#pragma unroll
        for (int ni = 0; ni < 2; ++ni) {
          const int col = n0 + nw + ni * 16 + lr;  // first of (d, d+32) pair
          const int j = ni * 16 + lr;              // 0..31 freq index
          const float c = tcos[pos * 32 + j];
          const float sn = tsin[pos * 32 + j];
          const float x1 = acc[mi][ni][r] + bias[col];
          const float x2 = acc[mi][ni + 2][r] + bias[col + 32];
          const int h = col >> 7, hd = col & 127;
          const size_t base = (((size_t)(b * H_ + h)) * S_ + s) * D_;
          out[base + hd] = (_Float16)(x1 * c - x2 * sn);
          out[base + hd + 32] = (_Float16)(x2 * c + x1 * sn);
        }
      }
    }
  }
}

// ---------------------------------------------------------------------------
// Fused flash attention, 2-phase double-buffered.
// Block = (b,h, 64 q-rows); 4 waves x 16 rows. Swapped MFMA operands
// (S layout [t][q], o layout [d][q]); LDS XOR-swizzled via pre-swizzled
// global_load_lds source. Per iteration: issue streams(t), issue STAGE(t+1)
// into the other buffer, compute(t), __syncthreads (sole drain), swap.
// ---------------------------------------------------------------------------
__global__ __launch_bounds__(256) void flash_kernel(
    const _Float16* __restrict__ q, const _Float16* __restrict__ k,
    const _Float16* __restrict__ vt, const float* __restrict__ pbias,
    const float* __restrict__ maskp, const float* __restrict__ prev,
    float* __restrict__ scores, _Float16* __restrict__ ctx) {
  constexpr int BT = 64;
  __shared__ _Float16 KsBuf[2][BT * D_];   // [t][d] swizzled, 2 x 16 KB
  __shared__ _Float16 VTsBuf[2][D_ * BT];  // [d][t] swizzled, 2 x 16 KB
  __shared__ _Float16 Ps[4][16 * BT];      // per-wave [q][t] swizzled, 8 KB

  const int tid = threadIdx.x, w = tid >> 6, l = tid & 63;
  const int lr = l & 15, lh = l >> 4;
  // XCD swizzle: 1024 blocks -> 128 consecutive per XCD (8 planes/XCD)
  const int sid = (blockIdx.x & 7) * 128 + (blockIdx.x >> 3);
  const int qt = sid & 15, byh = sid >> 4;
  const int b = byh >> 4, h = byh & 15;
  const size_t plane = (size_t)byh;
  const int q0 = qt * 64 + w * 16;
  const int qrow = q0 + lr;           // this lane's q-row
  const int swz = (lr & 7) << 3;      // element-index XOR for frag reads

  const float* prow  = prev  + (plane * S_ + qrow) * S_;
  const float* pbrow = pbias + ((size_t)h * S_ + qrow) * S_;
  const float* mrow  = maskp + ((size_t)b * S_ + qrow) * S_;
  float*       srow  = scores + (plane * S_ + qrow) * S_;
  const _Float16* kpl = k  + plane * S_ * D_;
  const _Float16* vpl = vt + plane * D_ * S_;

  // Q B-fragments: lane provides Q[row=lr][k]
  f16x8 qa[4];
#pragma unroll
  for (int kk = 0; kk < 4; ++kk)
    qa[kk] = *(const f16x8*)(q + (plane * S_ + qrow) * D_ + kk * 32 + lh * 8);

  f32x4 o[8] = {};
  float m_r = -1e30f, l_r = 0.0f;

  _Float16* ksA = &KsBuf[0][0];
  _Float16* ksB = &KsBuf[1][0];
  _Float16* vtA = &VTsBuf[0][0];
  _Float16* vtB = &VTsBuf[1][0];

  // prologue: stage tile 0 into buffer A
#pragma unroll
  for (int i = 0; i < 4; ++i) {
    const int e = i * 2048 + tid * 8;
    const int krow = e >> 7;
    gll16(kpl + (size_t)krow * D_ + ((e & 127) ^ ((krow & 7) << 3)), ksA + e);
    const int vrow = e >> 6;
    gll16(vpl + (size_t)vrow * S_ + ((e & 63) ^ ((vrow & 7) << 3)), vtA + e);
  }
  __syncthreads();   // compiler drains vmcnt before s_barrier

  for (int tt = 0; tt < S_ / BT; ++tt) {
    const int t0 = tt * BT;

    // streams for THIS tile (needed after QK^T; deepest-issued)
    f32x4 pv4[4], pb4[4], mk4[4];
#pragma unroll
    for (int nt = 0; nt < 4; ++nt) {
      const int toff = t0 + nt * 16 + lh * 4;
      pv4[nt] = __builtin_nontemporal_load((const f32x4*)(prow + toff));
      pb4[nt] = *(const f32x4*)(pbrow + toff);
      mk4[nt] = *(const f32x4*)(mrow + toff);
    }
    // STAGE next tile into the other buffer (async DMA, drained at the
    // end-of-iteration barrier after the whole compute phase)
    if (tt < 15) {
      const int t1 = t0 + BT;
#pragma unroll
      for (int i = 0; i < 4; ++i) {
        const int e = i * 2048 + tid * 8;
        const int krow = e >> 7;
        gll16(kpl + (size_t)(t1 + krow) * D_ + ((e & 127) ^ ((krow & 7) << 3)), ksB + e);
        const int vrow = e >> 6;
        gll16(vpl + (size_t)vrow * S_ + t1 + ((e & 63) ^ ((vrow & 7) << 3)), vtB + e);
      }
    }

    // QK^T swapped: sa[nt][r] = S[t = t0+nt*16+lh*4+r][q = qrow]
    f32x4 sa[4] = {};
    __builtin_amdgcn_s_setprio(1);
#pragma unroll
    for (int nt = 0; nt < 4; ++nt)
#pragma unroll
      for (int kk = 0; kk < 4; ++kk) {
        const int row = nt * 16 + lr;
        f16x8 kb = *(const f16x8*)(ksA + row * D_ + ((kk * 32 + lh * 8) ^ swz));
        sa[nt] = MFMA16(kb, qa[kk], sa[nt]);
      }
    __builtin_amdgcn_s_setprio(0);

    // epilogue: score = (qk+pb)/sqrtD + mask + prev ; pure VALU + store
#pragma unroll
    for (int nt = 0; nt < 4; ++nt) {
      const int toff = t0 + nt * 16 + lh * 4;
      f32x4 sc4 = (sa[nt] + pb4[nt]) * RSQRT_D + mk4[nt] + pv4[nt];
      __builtin_nontemporal_store(sc4, (f32x4*)(srow + toff));
      sa[nt] = sc4;
    }

    // online softmax, one q-row per lane; row group = lanes {l, l^16, l^32, l^48}
    float tmx = -1e30f;
#pragma unroll
    for (int nt = 0; nt < 4; ++nt)
#pragma unroll
      for (int r = 0; r < 4; ++r) tmx = fmaxf(tmx, sa[nt][r]);
    tmx = fmaxf(tmx, __shfl_xor(tmx, 16));
    tmx = fmaxf(tmx, __shfl_xor(tmx, 32));
    if (!__all(tmx <= m_r + 8.0f)) {   // T13 defer-max
      const float newm = fmaxf(m_r, tmx);
      const float al = __expf(m_r - newm);
      m_r = newm;
      l_r *= al;
#pragma unroll
      for (int nd = 0; nd < 8; ++nd) o[nd] *= al;
    }
    float ts = 0.0f;
#pragma unroll
    for (int nt = 0; nt < 4; ++nt)
#pragma unroll
      for (int r = 0; r < 4; ++r) {
        const float pe = __expf(sa[nt][r] - m_r);
        sa[nt][r] = pe;
        ts += pe;
      }
    ts += __shfl_xor(ts, 16);
    ts += __shfl_xor(ts, 32);
    l_r += ts;

    // P -> per-wave LDS [q=lr][t], swizzled, f16x4 stores (wave-local)
    _Float16* pw = &Ps[w][0];
#pragma unroll
    for (int nt = 0; nt < 4; ++nt) {
      f16x4 pk;
      pk[0] = (_Float16)sa[nt][0]; pk[1] = (_Float16)sa[nt][1];
      pk[2] = (_Float16)sa[nt][2]; pk[3] = (_Float16)sa[nt][3];
      *(f16x4*)(pw + lr * BT + ((nt * 16 + lh * 4) ^ swz)) = pk;
    }

    // PV swapped: o[nd][r] = ctx[d = nd*16+lh*4+r][q = qrow]
    __builtin_amdgcn_s_setprio(1);
#pragma unroll
    for (int kk2 = 0; kk2 < 2; ++kk2) {
      const f16x8 pa = *(const f16x8*)(pw + lr * BT + ((kk2 * 32 + lh * 8) ^ swz));
#pragma unroll
      for (int nd = 0; nd < 8; ++nd) {
        const int vr = nd * 16 + lr;
        const f16x8 vb = *(const f16x8*)(vtA + vr * BT + ((kk2 * 32 + lh * 8) ^ swz));
        o[nd] = MFMA16(vb, pa, o[nd]);
      }
    }
    __builtin_amdgcn_s_setprio(0);

    // sole drain point: waits this wave's gll16s + stores, then barrier
    __syncthreads();
    _Float16* t1p = ksA; ksA = ksB; ksB = t1p;
    _Float16* t2p = vtA; vtA = vtB; vtB = t2p;
  }

  // ctx write: lane owns q-row qrow, d = nd*16 + lh*4 + r -> f16x4 stores
  const float inv_l = 1.0f / l_r;
  _Float16* crow = ctx + ((size_t)(b * S_) + qrow) * HID_ + h * D_;
#pragma unroll
  for (int nd = 0; nd < 8; ++nd) {
    f16x4 cv;
#pragma unroll
    for (int r = 0; r < 4; ++r) cv[r] = (_Float16)(o[nd][r] * inv_l);
    *(f16x4*)(crow + nd * 16 + lh * 4) = cv;
  }
}

// ---------------------------------------------------------------------------
extern "C" void kernel_launch(void* const* d_in, const int* in_sizes, int n_in,
                              void* d_out, int out_size, void* d_ws, size_t ws_size,
                              hipStream_t stream) {
  const float* query = (const float*)d_in[0];
  const float* key_i = (const float*)d_in[1];
  const float* value = (const float*)d_in[2];
  const float* maskp = (const float*)d_in[3];
  const float* pbias = (const float*)d_in[4];
  const float* prev  = (const float*)d_in[5];
  const int*   pids  = (const int*)d_in[6];
  const float* Wq = (const float*)d_in[7];
  const float* bq = (const float*)d_in[8];
  const float* Wk = (const float*)d_in[9];
  const float* bk = (const float*)d_in[10];
  const float* Wv = (const float*)d_in[11];
  const float* bv = (const float*)d_in[12];
  const float* Wo = (const float*)d_in[13];
  const float* bo = (const float*)d_in[14];

  char* ws = (char*)d_ws;
  // workspace layout (bytes); total need = 134,479,872
  const size_t OFF_TCOS = 0;
  const size_t OFF_TSIN = 131072;
  const size_t OFF_W    = 262144;                      // 4 x 8 MB f16 weights
  const size_t OFF_X    = OFF_W + 4ull * 8388608;      // 3 x 16 MB f16 X
  const size_t OFF_Q    = OFF_X + 3ull * 16777216;
  const size_t OFF_K    = OFF_Q + 16777216;
  const size_t OFF_VT   = OFF_K + 16777216;            // V proj writes here (B,H,D,S)
  const size_t OFF_CTX  = OFF_X + 16777216;            // reuse Xk (consumed)

  float* tcos = (float*)(ws + OFF_TCOS);
  float* tsin = (float*)(ws + OFF_TSIN);
  _Float16* Wq16 = (_Float16*)(ws + OFF_W);
  _Float16* Wk16 = (_Float16*)(ws + OFF_W + 8388608);
  _Float16* Wv16 = (_Float16*)(ws + OFF_W + 2ull * 8388608);
  _Float16* Wo16 = (_Float16*)(ws + OFF_W + 3ull * 8388608);
  _Float16* Xq16 = (_Float16*)(ws + OFF_X);
  _Float16* Xk16 = (_Float16*)(ws + OFF_X + 16777216);
  _Float16* Xv16 = (_Float16*)(ws + OFF_X + 2ull * 16777216);
  _Float16* q16  = (_Float16*)(ws + OFF_Q);
  _Float16* k16  = (_Float16*)(ws + OFF_K);
  _Float16* vt16 = (_Float16*)(ws + OFF_VT);
  _Float16* ctx16 = (_Float16*)(ws + OFF_CTX);

  float* out_f32 = (float*)d_out;                 // (B,S,HID) = 8,388,608
  float* scores  = (float*)d_out + 8388608;       // (B,H,S,S) = 67,108,864

  rope_table_kernel<<<128, 256, 0, stream>>>(tcos, tsin);

  cvt_kernel<<<2048, 256, 0, stream>>>(Wq, Wq16, 524288);
  cvt_kernel<<<2048, 256, 0, stream>>>(Wk, Wk16, 524288);
  cvt_kernel<<<2048, 256, 0, stream>>>(Wv, Wv16, 524288);
  cvt_kernel<<<2048, 256, 0, stream>>>(Wo, Wo16, 524288);
  cvt_kernel<<<4096, 256, 0, stream>>>(query, Xq16, 1048576);
  cvt_kernel<<<4096, 256, 0, stream>>>(key_i, Xk16, 1048576);
  cvt_kernel<<<4096, 256, 0, stream>>>(value, Xv16, 1048576);

  proj_kernel<0><<<512, 256, 0, stream>>>(Xq16, Wq16, bq, (void*)q16, pids, tcos, tsin);
  proj_kernel<0><<<512, 256, 0, stream>>>(Xk16, Wk16, bk, (void*)k16, pids, tcos, tsin);
  proj_kernel<1><<<512, 256, 0, stream>>>(Xv16, Wv16, bv, (void*)vt16, nullptr, nullptr, nullptr);

  flash_kernel<<<1024, 256, 0, stream>>>(q16, k16, vt16, pbias, maskp, prev,
                                         scores, ctx16);

  proj_kernel<2><<<512, 256, 0, stream>>>(ctx16, Wo16, bo, (void*)out_f32,
                                          nullptr, nullptr, nullptr);
}